// Round 15
// baseline (181.414 us; speedup 1.0000x reference)
//
#include <hip/hip_runtime.h>
#include <hip/hip_bf16.h>

// Problem constants
#define HID 512
#define SEQ 2048
#define NG 32            // (B*NUM_HEADS) after the faithful-to-source flat reshape
#define HD 64
#define MROWS 8192       // B*SEQ
#define LDP 72           // padded LDS row stride (elems) = 144B
// 1/sqrt(512) * log2(e): folded into Q so softmax is exp2(s)
#define QSC 0.0637587178f

typedef __bf16 bf16x8 __attribute__((ext_vector_type(8)));
typedef float f32x4 __attribute__((ext_vector_type(4)));

#define MFMA(a, b, c) __builtin_amdgcn_mfma_f32_16x16x32_bf16((a), (b), (c), 0, 0, 0)

// ---------------------------------------------------------------------------
// prep: f32 -> bf16 vectorized converts
// ---------------------------------------------------------------------------
__global__ __launch_bounds__(256) void conv_x(const float* __restrict__ src,
                                              __hip_bfloat16* __restrict__ dst, int n4) {
    int stride = gridDim.x * 256;
    for (int i = blockIdx.x * 256 + threadIdx.x; i < n4; i += stride) {
        float4 v = *(const float4*)(src + (size_t)i * 4);
        union { __hip_bfloat16 h[4]; uint2 u; } p;
        p.h[0] = __float2bfloat16(v.x); p.h[1] = __float2bfloat16(v.y);
        p.h[2] = __float2bfloat16(v.z); p.h[3] = __float2bfloat16(v.w);
        *(uint2*)(dst + (size_t)i * 4) = p.u;
    }
}

__global__ __launch_bounds__(256) void conv_w(const float* __restrict__ a,
                                              const float* __restrict__ b,
                                              const float* __restrict__ c,
                                              const float* __restrict__ d,
                                              __hip_bfloat16* __restrict__ out) {
    int which = blockIdx.y;
    const float* s = which == 0 ? a : (which == 1 ? b : (which == 2 ? c : d));
    __hip_bfloat16* o = out + (size_t)which * (HID * HID);
    int i = blockIdx.x * 256 + threadIdx.x;   // 65536 float4 per W
    float4 v = *(const float4*)(s + (size_t)i * 4);
    union { __hip_bfloat16 h[4]; uint2 u; } p;
    p.h[0] = __float2bfloat16(v.x); p.h[1] = __float2bfloat16(v.y);
    p.h[2] = __float2bfloat16(v.z); p.h[3] = __float2bfloat16(v.w);
    *(uint2*)(o + (size_t)i * 4) = p.u;
}

// ---------------------------------------------------------------------------
// QKV as ONE concat GEMM: Wcat = [Wq;Wk;Wv] rows n in [0,1536) (contiguous in
// ws by construction). 128x128 tile, 4 waves in 2x2, 4x4 acc/wave: 32 MFMA
// per 16 fragment-reads per k-step (2x the MFMA issue density of the old
// 64x64 tiles — the GEMMs were instruction-bound, not memory-bound).
// which = col0>>9 is uniform per block (128 | 512): q (scaled QSC) / k / vT.
// ---------------------------------------------------------------------------
__global__ __launch_bounds__(256) void gemm_qkv2(
        const __hip_bfloat16* __restrict__ Xb, const __hip_bfloat16* __restrict__ Wc,
        const float* __restrict__ bq, const float* __restrict__ bk, const float* __restrict__ bv,
        __hip_bfloat16* __restrict__ qout, __hip_bfloat16* __restrict__ kout,
        __hip_bfloat16* __restrict__ vT) {
    __shared__ __hip_bfloat16 Xs[128][LDP];
    __shared__ __hip_bfloat16 Ws[128][LDP];
    const int tid = threadIdx.x;
    const int w = tid >> 6, l = tid & 63;
    const int h = l >> 4, q = l & 15;
    const int wr = w & 1, wc = w >> 1;
    const int row0 = blockIdx.x * 128, col0 = blockIdx.y * 128;

    // staging coords: col constant per thread; rows rb, rb+32, rb+64, rb+96
    const int rb = tid >> 3;
    const int col = (tid & 7) * 8;

    uint4 px[4], pw[4];
#pragma unroll
    for (int ii = 0; ii < 4; ++ii) {
        int r = rb + ii * 32;
        px[ii] = *(const uint4*)(Xb + (size_t)(row0 + r) * HID + col);
        pw[ii] = *(const uint4*)(Wc + (size_t)(col0 + r) * HID + col);
    }

    f32x4 acc[4][4] = {};
    for (int kt = 0; kt < 8; ++kt) {
        __syncthreads();
#pragma unroll
        for (int ii = 0; ii < 4; ++ii) {
            int r = rb + ii * 32;
            *(uint4*)&Xs[r][col] = px[ii];
            *(uint4*)&Ws[r][col] = pw[ii];
        }
        __syncthreads();
        if (kt < 7) {
            size_t go = (size_t)(kt + 1) * 64 + col;
#pragma unroll
            for (int ii = 0; ii < 4; ++ii) {
                int r = rb + ii * 32;
                px[ii] = *(const uint4*)(Xb + (size_t)(row0 + r) * HID + go);
                pw[ii] = *(const uint4*)(Wc + (size_t)(col0 + r) * HID + go);
            }
        }
#pragma unroll
        for (int dk = 0; dk < 2; ++dk) {
            bf16x8 a[4], b[4];
#pragma unroll
            for (int mi = 0; mi < 4; ++mi)
                a[mi] = *(const bf16x8*)&Xs[wr * 64 + mi * 16 + q][dk * 32 + 8 * h];
#pragma unroll
            for (int ni = 0; ni < 4; ++ni)
                b[ni] = *(const bf16x8*)&Ws[wc * 64 + ni * 16 + q][dk * 32 + 8 * h];
#pragma unroll
            for (int mi = 0; mi < 4; ++mi)
#pragma unroll
                for (int ni = 0; ni < 4; ++ni)
                    acc[mi][ni] = MFMA(a[mi], b[ni], acc[mi][ni]);
        }
    }

    const int which = col0 >> 9;   // uniform per block: 0=q, 1=k, 2=v
    if (which < 2) {
        __hip_bfloat16* dst = which ? kout : qout;
        const float* bias = which ? bk : bq;
        const float sc = which ? 1.0f : QSC;
#pragma unroll
        for (int ni = 0; ni < 4; ++ni) {
            int nn = (col0 & 511) + wc * 64 + ni * 16 + q;
            float bvv = bias[nn];
#pragma unroll
            for (int mi = 0; mi < 4; ++mi)
#pragma unroll
                for (int jj = 0; jj < 4; ++jj) {
                    int r = row0 + wr * 64 + mi * 16 + 4 * h + jj;
                    dst[(size_t)r * HID + nn] =
                        __float2bfloat16((acc[mi][ni][jj] + bvv) * sc);
                }
        }
    } else {
        const int g = row0 >> 8;   // 128-row tile stays inside one head
#pragma unroll
        for (int ni = 0; ni < 4; ++ni) {
            int nn = (col0 & 511) + wc * 64 + ni * 16 + q;
            float bvv = bv[nn];
            int d = nn & 63, icol = nn >> 6;
#pragma unroll
            for (int mi = 0; mi < 4; ++mi)
#pragma unroll
                for (int jj = 0; jj < 4; ++jj) {
                    int r = row0 + wr * 64 + mi * 16 + 4 * h + jj;
                    int i = ((r & 255) << 3) + icol;
                    vT[(size_t)g * (HD * SEQ) + (size_t)d * SEQ + i] =
                        __float2bfloat16(acc[mi][ni][jj] + bvv);
                }
        }
    }
}

// ---------------------------------------------------------------------------
// GEMM: out_f32[M x 512] = X_bf16 @ Wo_bf16^T + bo. 128x128 tile, 4x4 acc.
// ---------------------------------------------------------------------------
__global__ __launch_bounds__(256) void gemm_out2(const __hip_bfloat16* __restrict__ X,
                                                 const __hip_bfloat16* __restrict__ W,
                                                 const float* __restrict__ bias,
                                                 float* __restrict__ out) {
    __shared__ __hip_bfloat16 Xs[128][LDP];
    __shared__ __hip_bfloat16 Ws[128][LDP];
    const int tid = threadIdx.x;
    const int w = tid >> 6, l = tid & 63;
    const int h = l >> 4, q = l & 15;
    const int wr = w & 1, wc = w >> 1;
    const int row0 = blockIdx.x * 128, col0 = blockIdx.y * 128;

    const int rb = tid >> 3;
    const int col = (tid & 7) * 8;

    uint4 px[4], pw[4];
#pragma unroll
    for (int ii = 0; ii < 4; ++ii) {
        int r = rb + ii * 32;
        px[ii] = *(const uint4*)(X + (size_t)(row0 + r) * HID + col);
        pw[ii] = *(const uint4*)(W + (size_t)(col0 + r) * HID + col);
    }

    f32x4 acc[4][4] = {};
    for (int kt = 0; kt < 8; ++kt) {
        __syncthreads();
#pragma unroll
        for (int ii = 0; ii < 4; ++ii) {
            int r = rb + ii * 32;
            *(uint4*)&Xs[r][col] = px[ii];
            *(uint4*)&Ws[r][col] = pw[ii];
        }
        __syncthreads();
        if (kt < 7) {
            size_t go = (size_t)(kt + 1) * 64 + col;
#pragma unroll
            for (int ii = 0; ii < 4; ++ii) {
                int r = rb + ii * 32;
                px[ii] = *(const uint4*)(X + (size_t)(row0 + r) * HID + go);
                pw[ii] = *(const uint4*)(W + (size_t)(col0 + r) * HID + go);
            }
        }
#pragma unroll
        for (int dk = 0; dk < 2; ++dk) {
            bf16x8 a[4], b[4];
#pragma unroll
            for (int mi = 0; mi < 4; ++mi)
                a[mi] = *(const bf16x8*)&Xs[wr * 64 + mi * 16 + q][dk * 32 + 8 * h];
#pragma unroll
            for (int ni = 0; ni < 4; ++ni)
                b[ni] = *(const bf16x8*)&Ws[wc * 64 + ni * 16 + q][dk * 32 + 8 * h];
#pragma unroll
            for (int mi = 0; mi < 4; ++mi)
#pragma unroll
                for (int ni = 0; ni < 4; ++ni)
                    acc[mi][ni] = MFMA(a[mi], b[ni], acc[mi][ni]);
        }
    }
#pragma unroll
    for (int ni = 0; ni < 4; ++ni) {
        int n = col0 + wc * 64 + ni * 16 + q;
        float bvv = bias[n];
#pragma unroll
        for (int mi = 0; mi < 4; ++mi)
#pragma unroll
            for (int jj = 0; jj < 4; ++jj) {
                int r = row0 + wr * 64 + mi * 16 + 4 * h + jj;
                out[(size_t)r * HID + n] = acc[mi][ni][jj] + bvv;
            }
    }
}

// ---------------------------------------------------------------------------
// Attention — round-12 checkpoint (best: 65.3 us). Swapped-QK^T in-register
// softmax: S^T = MFMA(K, Q); lane (h, q=l&15) holds P for query q at exactly
// the keys its PV A-fragment needs, given V staged with column permutation
//   K_id(c) = 16*(c>>5) + 32*((c&7)>>2) + 4*((c>>3)&3) + (c&3).
// P never touches LDS. K/V/sbias double-buffered -> ONE barrier per k-tile.
// Mask enters as the S^T accumulator init; row-sums via all-ones MFMA.
// ---------------------------------------------------------------------------
__global__ __launch_bounds__(256) void attn(const __hip_bfloat16* __restrict__ qg,
                                            const __hip_bfloat16* __restrict__ kg,
                                            const __hip_bfloat16* __restrict__ vT,
                                            const int* __restrict__ mask,
                                            __hip_bfloat16* __restrict__ wvt) {
    __shared__ __hip_bfloat16 Ks[2][64][LDP];
    __shared__ __hip_bfloat16 VTs[2][64][LDP];
    __shared__ float sb[2][64];

    const int tid = threadIdx.x;
    const int w = tid >> 6, l = tid & 63;
    const int h = l >> 4, q = l & 15;
    // XCD-chunked swizzle: 512 blocks % 8 == 0 -> bijective
    const int bid = (blockIdx.x & 7) * 64 + (blockIdx.x >> 3);
    const int g = bid >> 4, qt = bid & 15;
    const size_t hb = (size_t)g * (SEQ * HD);

    // Q fragments in registers (one-time global read, L2-resident)
    bf16x8 qf[2][2];
    for (int m = 0; m < 2; ++m)
        for (int dk = 0; dk < 2; ++dk)
            qf[m][dk] = *(const bf16x8*)(qg + hb +
                (size_t)(qt * 128 + w * 32 + m * 16 + q) * HD + dk * 32 + 8 * h);

    const int r0 = tid >> 3, r1 = (tid + 256) >> 3;
    const int cc0 = (tid & 7) * 8;
    // permuted V dest base: keys cc0..cc0+3 -> cA..cA+3, cc0+4..+7 -> cA+8..+11
    const int ntc = cc0 >> 4;
    const int cA = (ntc & 1) * 32 + ((cc0 >> 2) & 3) * 8 + (ntc >> 1) * 4;

    const __bf16 kOne = (__bf16)1.0f;
    const bf16x8 ones = {kOne, kOne, kOne, kOne, kOne, kOne, kOne, kOne};

    f32x4 acc[2][4] = {};
    f32x4 lsum[2] = {};

    // ---- prologue: tile 0 into buf 0; tile 1 into regs ----
    uint4 kp0 = *(const uint4*)(kg + hb + (size_t)r0 * HD + cc0);
    uint4 kp1 = *(const uint4*)(kg + hb + (size_t)r1 * HD + cc0);
    uint4 vp0 = *(const uint4*)(vT + hb + (size_t)r0 * SEQ + cc0);
    uint4 vp1 = *(const uint4*)(vT + hb + (size_t)r1 * SEQ + cc0);
    int mpre = (tid < 64) ? mask[tid] : 0;

    *(uint4*)&Ks[0][r0][cc0] = kp0;
    *(uint4*)&Ks[0][r1][cc0] = kp1;
    *(uint2*)&VTs[0][r0][cA]     = make_uint2(vp0.x, vp0.y);
    *(uint2*)&VTs[0][r0][cA + 8] = make_uint2(vp0.z, vp0.w);
    *(uint2*)&VTs[0][r1][cA]     = make_uint2(vp1.x, vp1.y);
    *(uint2*)&VTs[0][r1][cA + 8] = make_uint2(vp1.z, vp1.w);
    if (tid < 64) sb[0][tid] = mpre ? 0.f : -1e38f;

    kp0 = *(const uint4*)(kg + hb + (size_t)(64 * HD) + (size_t)r0 * HD + cc0);
    kp1 = *(const uint4*)(kg + hb + (size_t)(64 * HD) + (size_t)r1 * HD + cc0);
    vp0 = *(const uint4*)(vT + hb + (size_t)r0 * SEQ + 64 + cc0);
    vp1 = *(const uint4*)(vT + hb + (size_t)r1 * SEQ + 64 + cc0);
    if (tid < 64) mpre = mask[64 + tid];
    __syncthreads();

    for (int kt = 0; kt < 32; ++kt) {
        const int cur = kt & 1;
        if (kt < 31) {
            *(uint4*)&Ks[cur ^ 1][r0][cc0] = kp0;
            *(uint4*)&Ks[cur ^ 1][r1][cc0] = kp1;
            *(uint2*)&VTs[cur ^ 1][r0][cA]     = make_uint2(vp0.x, vp0.y);
            *(uint2*)&VTs[cur ^ 1][r0][cA + 8] = make_uint2(vp0.z, vp0.w);
            *(uint2*)&VTs[cur ^ 1][r1][cA]     = make_uint2(vp1.x, vp1.y);
            *(uint2*)&VTs[cur ^ 1][r1][cA + 8] = make_uint2(vp1.z, vp1.w);
            if (tid < 64) sb[cur ^ 1][tid] = mpre ? 0.f : -1e38f;
        }
        if (kt < 30) {
            const size_t ko = hb + (size_t)(kt + 2) * 64 * HD;
            kp0 = *(const uint4*)(kg + ko + (size_t)r0 * HD + cc0);
            kp1 = *(const uint4*)(kg + ko + (size_t)r1 * HD + cc0);
            vp0 = *(const uint4*)(vT + hb + (size_t)r0 * SEQ + (kt + 2) * 64 + cc0);
            vp1 = *(const uint4*)(vT + hb + (size_t)r1 * SEQ + (kt + 2) * 64 + cc0);
            if (tid < 64) mpre = mask[(kt + 2) * 64 + tid];
        }

        // S^T = K Q^T, accumulator init = per-key mask bias (vector read)
        f32x4 sacc[2][4];
        for (int nt = 0; nt < 4; ++nt) {
            f32x4 binit = *(const f32x4*)&sb[cur][nt * 16 + 4 * h];
            sacc[0][nt] = binit;
            sacc[1][nt] = binit;
        }
        for (int dk = 0; dk < 2; ++dk) {
            for (int nt = 0; nt < 4; ++nt) {
                bf16x8 kf = *(const bf16x8*)&Ks[cur][nt * 16 + q][dk * 32 + 8 * h];
                sacc[0][nt] = MFMA(kf, qf[0][dk], sacc[0][nt]);
                sacc[1][nt] = MFMA(kf, qf[1][dk], sacc[1][nt]);
            }
        }
        // p = exp2(s^T) packed straight into PV A-fragments (in registers)
        union pk_t { bf16x8 v; __hip_bfloat16 hh[8]; } pa[2][2];
        for (int m = 0; m < 2; ++m)
            for (int kk = 0; kk < 2; ++kk)
                for (int j = 0; j < 4; ++j) {
                    pa[m][kk].hh[j]     = __float2bfloat16(exp2f(sacc[m][kk][j]));
                    pa[m][kk].hh[j + 4] = __float2bfloat16(exp2f(sacc[m][kk + 2][j]));
                }
        // acc += P @ V ; lsum += P @ ones  (V columns permuted to match)
        for (int kk = 0; kk < 2; ++kk) {
            lsum[0] = MFMA(pa[0][kk].v, ones, lsum[0]);
            lsum[1] = MFMA(pa[1][kk].v, ones, lsum[1]);
            for (int dt = 0; dt < 4; ++dt) {
                bf16x8 bv = *(const bf16x8*)&VTs[cur][dt * 16 + q][kk * 32 + 8 * h];
                acc[0][dt] = MFMA(pa[0][kk].v, bv, acc[0][dt]);
                acc[1][dt] = MFMA(pa[1][kk].v, bv, acc[1][dt]);
            }
        }
        __syncthreads();   // writes to buf[cur^1] done; reads of buf[cur] done
    }

    // lane's lsum[m][jj] IS the row-sum for acc row jj of subtile m
    for (int m = 0; m < 2; ++m) {
        float rinv[4];
        for (int jj = 0; jj < 4; ++jj) rinv[jj] = 1.f / lsum[m][jj];
        const int ibase = qt * 128 + w * 32 + m * 16 + 4 * h;
        for (int dt = 0; dt < 4; ++dt) {
            int d = dt * 16 + q;
            union { __hip_bfloat16 hh[4]; uint2 u; } o;
            for (int jj = 0; jj < 4; ++jj)
                o.hh[jj] = __float2bfloat16(acc[m][dt][jj] * rinv[jj]);
            *(uint2*)(wvt + (size_t)g * (HD * SEQ) + (size_t)d * SEQ + ibase) = o.u;
        }
    }
}

// ---------------------------------------------------------------------------
// ws layout (26 MB peak): Xb [0,8MB) -> aliased by wvt after QKV GEMM;
// W bf16 [8,10MB) (Wq,Wk,Wv contiguous = concat GEMM operand, then Wo);
// qb [10,18MB); kb [18,26MB).
// vT lives in d_out's first 8 MB (dead before gemm_out overwrites d_out).
// ---------------------------------------------------------------------------
extern "C" void kernel_launch(void* const* d_in, const int* in_sizes, int n_in,
                              void* d_out, int out_size, void* d_ws, size_t ws_size,
                              hipStream_t stream) {
    const float* lstm = (const float*)d_in[0];
    const int* mask = (const int*)d_in[1];
    const float* Wq = (const float*)d_in[2]; const float* bq = (const float*)d_in[3];
    const float* Wk = (const float*)d_in[4]; const float* bk = (const float*)d_in[5];
    const float* Wv = (const float*)d_in[6]; const float* bv = (const float*)d_in[7];
    const float* Wo = (const float*)d_in[8]; const float* bo = (const float*)d_in[9];
    float* out = (float*)d_out;

    const size_t NX = (size_t)MROWS * HID;    // 4M elems
    const size_t NW = (size_t)HID * HID;      // 256K elems
    __hip_bfloat16* Xb  = (__hip_bfloat16*)d_ws;            // 4M elems (8MB)
    __hip_bfloat16* Wqb = Xb + NX;                          // 256K (Wcat base)
    __hip_bfloat16* Wob = Wqb + 3 * NW;
    __hip_bfloat16* qb  = Wob + NW;                         // 4M
    __hip_bfloat16* kb  = qb + NX;                          // 4M
    __hip_bfloat16* vT  = (__hip_bfloat16*)d_out;           // scratch in d_out[0,8MB)
    __hip_bfloat16* wvt = Xb;                               // alias: Xb dead after QKV GEMM

    conv_x<<<2048, 256, 0, stream>>>(lstm, Xb, (int)(NX / 4));
    conv_w<<<dim3(256, 4), 256, 0, stream>>>(Wq, Wk, Wv, Wo, Wqb);

    gemm_qkv2<<<dim3(64, 12), 256, 0, stream>>>(Xb, Wqb, bq, bk, bv, qb, kb, vT);
    attn<<<dim3(NG * (SEQ / 128)), 256, 0, stream>>>(qb, kb, vT, mask, wvt);
    gemm_out2<<<dim3(64, 4), 256, 0, stream>>>(wvt, Wob, bo, out);
}

// Round 16
// 116.763 us; speedup vs baseline: 1.5537x; 1.5537x over previous
//
#include <hip/hip_runtime.h>
#include <hip/hip_bf16.h>

// Problem constants
#define HID 512
#define SEQ 2048
#define NG 32            // (B*NUM_HEADS) after the faithful-to-source flat reshape
#define HD 64
#define MROWS 8192       // B*SEQ
#define LDP 72           // padded LDS row stride (elems) = 144B
// 1/sqrt(512) * log2(e): folded into Q so softmax is exp2(s)
#define QSC 0.0637587178f

typedef __bf16 bf16x8 __attribute__((ext_vector_type(8)));
typedef float f32x4 __attribute__((ext_vector_type(4)));

#define MFMA(a, b, c) __builtin_amdgcn_mfma_f32_16x16x32_bf16((a), (b), (c), 0, 0, 0)

// ---------------------------------------------------------------------------
// prep: f32 -> bf16 vectorized converts
// ---------------------------------------------------------------------------
__global__ __launch_bounds__(256) void conv_x(const float* __restrict__ src,
                                              __hip_bfloat16* __restrict__ dst, int n4) {
    int stride = gridDim.x * 256;
    for (int i = blockIdx.x * 256 + threadIdx.x; i < n4; i += stride) {
        float4 v = *(const float4*)(src + (size_t)i * 4);
        union { __hip_bfloat16 h[4]; uint2 u; } p;
        p.h[0] = __float2bfloat16(v.x); p.h[1] = __float2bfloat16(v.y);
        p.h[2] = __float2bfloat16(v.z); p.h[3] = __float2bfloat16(v.w);
        *(uint2*)(dst + (size_t)i * 4) = p.u;
    }
}

__global__ __launch_bounds__(256) void conv_w(const float* __restrict__ a,
                                              const float* __restrict__ b,
                                              const float* __restrict__ c,
                                              const float* __restrict__ d,
                                              __hip_bfloat16* __restrict__ out) {
    int which = blockIdx.y;
    const float* s = which == 0 ? a : (which == 1 ? b : (which == 2 ? c : d));
    __hip_bfloat16* o = out + (size_t)which * (HID * HID);
    int i = blockIdx.x * 256 + threadIdx.x;   // 65536 float4 per W
    float4 v = *(const float4*)(s + (size_t)i * 4);
    union { __hip_bfloat16 h[4]; uint2 u; } p;
    p.h[0] = __float2bfloat16(v.x); p.h[1] = __float2bfloat16(v.y);
    p.h[2] = __float2bfloat16(v.z); p.h[3] = __float2bfloat16(v.w);
    *(uint2*)(o + (size_t)i * 4) = p.u;
}

// ---------------------------------------------------------------------------
// Fused QKV GEMM (round-12 structure) with SWAPPED MFMA operands:
// acc = MFMA(W_frag, X_frag) -> lane's 4 acc values span 4 CONSECUTIVE output
// COLUMNS (n = col0 + nt*16 + 4h + jj), so q/k stores are uint2 (8B) instead
// of 4 scalar 2B stores at 1KB stride (round-15 lesson: epilogue stores are a
// first-order cost; 128^2 rewrite was store-bound at 122MB WRITE_SIZE).
// Lane's output row m = row0 + w*16 + (l&15). vT stays a 2B scatter.
// ---------------------------------------------------------------------------
__global__ __launch_bounds__(256) void gemm_qkv_fused(
        const __hip_bfloat16* __restrict__ Xb,
        const __hip_bfloat16* __restrict__ Wqb, const __hip_bfloat16* __restrict__ Wkb,
        const __hip_bfloat16* __restrict__ Wvb,
        const float* __restrict__ bq, const float* __restrict__ bk, const float* __restrict__ bv,
        __hip_bfloat16* __restrict__ qout, __hip_bfloat16* __restrict__ kout,
        __hip_bfloat16* __restrict__ vT) {
    __shared__ __hip_bfloat16 Xs[64][LDP];
    __shared__ __hip_bfloat16 Wqs[64][LDP];
    __shared__ __hip_bfloat16 Wks[64][LDP];
    __shared__ __hip_bfloat16 Wvs[64][LDP];
    const int tid = threadIdx.x;
    const int w = tid >> 6, l = tid & 63;
    const int h = l >> 4, q = l & 15;
    const int row0 = blockIdx.x * 64, col0 = blockIdx.y * 64;

    const int r0 = tid >> 3, r1 = (tid + 256) >> 3;
    const int cc0 = (tid & 7) * 8;
    uint4 px0, px1, pq0, pq1, pk0, pk1, pv0, pv1;
    {
        px0 = *(const uint4*)(Xb  + (size_t)(row0 + r0) * HID + cc0);
        px1 = *(const uint4*)(Xb  + (size_t)(row0 + r1) * HID + cc0);
        pq0 = *(const uint4*)(Wqb + (size_t)(col0 + r0) * HID + cc0);
        pq1 = *(const uint4*)(Wqb + (size_t)(col0 + r1) * HID + cc0);
        pk0 = *(const uint4*)(Wkb + (size_t)(col0 + r0) * HID + cc0);
        pk1 = *(const uint4*)(Wkb + (size_t)(col0 + r1) * HID + cc0);
        pv0 = *(const uint4*)(Wvb + (size_t)(col0 + r0) * HID + cc0);
        pv1 = *(const uint4*)(Wvb + (size_t)(col0 + r1) * HID + cc0);
    }

    f32x4 aq[4] = {}, ak[4] = {}, av[4] = {};
    for (int kt = 0; kt < 8; ++kt) {
        __syncthreads();
        *(uint4*)&Xs[r0][cc0]  = px0;  *(uint4*)&Xs[r1][cc0]  = px1;
        *(uint4*)&Wqs[r0][cc0] = pq0;  *(uint4*)&Wqs[r1][cc0] = pq1;
        *(uint4*)&Wks[r0][cc0] = pk0;  *(uint4*)&Wks[r1][cc0] = pk1;
        *(uint4*)&Wvs[r0][cc0] = pv0;  *(uint4*)&Wvs[r1][cc0] = pv1;
        __syncthreads();
        if (kt < 7) {
            size_t go = (size_t)(kt + 1) * 64 + cc0;
            px0 = *(const uint4*)(Xb  + (size_t)(row0 + r0) * HID + go);
            px1 = *(const uint4*)(Xb  + (size_t)(row0 + r1) * HID + go);
            pq0 = *(const uint4*)(Wqb + (size_t)(col0 + r0) * HID + go);
            pq1 = *(const uint4*)(Wqb + (size_t)(col0 + r1) * HID + go);
            pk0 = *(const uint4*)(Wkb + (size_t)(col0 + r0) * HID + go);
            pk1 = *(const uint4*)(Wkb + (size_t)(col0 + r1) * HID + go);
            pv0 = *(const uint4*)(Wvb + (size_t)(col0 + r0) * HID + go);
            pv1 = *(const uint4*)(Wvb + (size_t)(col0 + r1) * HID + go);
        }
        for (int dk = 0; dk < 2; ++dk) {
            bf16x8 x = *(const bf16x8*)&Xs[w * 16 + q][dk * 32 + 8 * h];
            for (int nt = 0; nt < 4; ++nt) {
                int rr = nt * 16 + q, cc = dk * 32 + 8 * h;
                aq[nt] = MFMA(*(const bf16x8*)&Wqs[rr][cc], x, aq[nt]);
                ak[nt] = MFMA(*(const bf16x8*)&Wks[rr][cc], x, ak[nt]);
                av[nt] = MFMA(*(const bf16x8*)&Wvs[rr][cc], x, av[nt]);
            }
        }
    }
    // epilogue (swapped layout): lane row m = row0 + w*16 + q;
    // cols n = col0 + nt*16 + 4h + jj (jj consecutive -> vector stores)
    const int m = row0 + w * 16 + q;
    const int g = row0 >> 8;
    const int irow = ((m & 255) << 3) + (int)blockIdx.y;   // vT i-index
    for (int nt = 0; nt < 4; ++nt) {
        int nb = col0 + nt * 16 + 4 * h;
        float4 b4q = *(const float4*)(bq + nb);
        float4 b4k = *(const float4*)(bk + nb);
        float4 b4v = *(const float4*)(bv + nb);
        const float* bqf = (const float*)&b4q;
        const float* bkf = (const float*)&b4k;
        const float* bvf = (const float*)&b4v;
        union { __hip_bfloat16 hh[4]; uint2 u; } oq, ok;
        for (int jj = 0; jj < 4; ++jj) {
            oq.hh[jj] = __float2bfloat16((aq[nt][jj] + bqf[jj]) * QSC);
            ok.hh[jj] = __float2bfloat16(ak[nt][jj] + bkf[jj]);
        }
        *(uint2*)(qout + (size_t)m * HID + nb) = oq.u;
        *(uint2*)(kout + (size_t)m * HID + nb) = ok.u;
        int db = nb & 63;   // col0 is a multiple of 64
        for (int jj = 0; jj < 4; ++jj)
            vT[(size_t)g * (HD * SEQ) + (size_t)(db + jj) * SEQ + irow] =
                __float2bfloat16(av[nt][jj] + bvf[jj]);
    }
}

// ---------------------------------------------------------------------------
// GEMM: out_f32[M x 512] = X_bf16 @ Wo_bf16^T + bo. Swapped operands ->
// float4 (16B) contiguous output stores.
// ---------------------------------------------------------------------------
__global__ __launch_bounds__(256) void gemm_out(const __hip_bfloat16* __restrict__ X,
                                                const __hip_bfloat16* __restrict__ W,
                                                const float* __restrict__ bias,
                                                float* __restrict__ out) {
    __shared__ __hip_bfloat16 Xs[64][LDP];
    __shared__ __hip_bfloat16 Ws[64][LDP];
    const int tid = threadIdx.x;
    const int w = tid >> 6, l = tid & 63;
    const int h = l >> 4, q = l & 15;
    const int row0 = blockIdx.x * 64, col0 = blockIdx.y * 64;

    const int r0 = tid >> 3, r1 = (tid + 256) >> 3;
    const int cc0 = (tid & 7) * 8;
    uint4 px0 = *(const uint4*)(X + (size_t)(row0 + r0) * HID + cc0);
    uint4 px1 = *(const uint4*)(X + (size_t)(row0 + r1) * HID + cc0);
    uint4 pw0 = *(const uint4*)(W + (size_t)(col0 + r0) * HID + cc0);
    uint4 pw1 = *(const uint4*)(W + (size_t)(col0 + r1) * HID + cc0);

    f32x4 acc[4] = {};
    for (int kt = 0; kt < 8; ++kt) {
        __syncthreads();
        *(uint4*)&Xs[r0][cc0] = px0;  *(uint4*)&Xs[r1][cc0] = px1;
        *(uint4*)&Ws[r0][cc0] = pw0;  *(uint4*)&Ws[r1][cc0] = pw1;
        __syncthreads();
        if (kt < 7) {
            size_t go = (size_t)(kt + 1) * 64 + cc0;
            px0 = *(const uint4*)(X + (size_t)(row0 + r0) * HID + go);
            px1 = *(const uint4*)(X + (size_t)(row0 + r1) * HID + go);
            pw0 = *(const uint4*)(W + (size_t)(col0 + r0) * HID + go);
            pw1 = *(const uint4*)(W + (size_t)(col0 + r1) * HID + go);
        }
        for (int dk = 0; dk < 2; ++dk) {
            bf16x8 x = *(const bf16x8*)&Xs[w * 16 + q][dk * 32 + 8 * h];
            for (int nt = 0; nt < 4; ++nt) {
                bf16x8 b = *(const bf16x8*)&Ws[nt * 16 + q][dk * 32 + 8 * h];
                acc[nt] = MFMA(b, x, acc[nt]);
            }
        }
    }
    const int m = row0 + w * 16 + q;
    for (int nt = 0; nt < 4; ++nt) {
        int nb = col0 + nt * 16 + 4 * h;
        float4 b4 = *(const float4*)(bias + nb);
        float4 o = make_float4(acc[nt][0] + b4.x, acc[nt][1] + b4.y,
                               acc[nt][2] + b4.z, acc[nt][3] + b4.w);
        *(float4*)(out + (size_t)m * HID + nb) = o;
    }
}

// ---------------------------------------------------------------------------
// Attention — round-12 checkpoint (best: 65.3 us). Swapped-QK^T in-register
// softmax: S^T = MFMA(K, Q); lane (h, q=l&15) holds P for query q at exactly
// the keys its PV A-fragment needs, given V staged with column permutation
//   K_id(c) = 16*(c>>5) + 32*((c&7)>>2) + 4*((c>>3)&3) + (c&3).
// P never touches LDS. K/V/sbias double-buffered -> ONE barrier per k-tile.
// Mask enters as the S^T accumulator init; row-sums via all-ones MFMA.
// ---------------------------------------------------------------------------
__global__ __launch_bounds__(256) void attn(const __hip_bfloat16* __restrict__ qg,
                                            const __hip_bfloat16* __restrict__ kg,
                                            const __hip_bfloat16* __restrict__ vT,
                                            const int* __restrict__ mask,
                                            __hip_bfloat16* __restrict__ wvt) {
    __shared__ __hip_bfloat16 Ks[2][64][LDP];
    __shared__ __hip_bfloat16 VTs[2][64][LDP];
    __shared__ float sb[2][64];

    const int tid = threadIdx.x;
    const int w = tid >> 6, l = tid & 63;
    const int h = l >> 4, q = l & 15;
    // XCD-chunked swizzle: 512 blocks % 8 == 0 -> bijective
    const int bid = (blockIdx.x & 7) * 64 + (blockIdx.x >> 3);
    const int g = bid >> 4, qt = bid & 15;
    const size_t hb = (size_t)g * (SEQ * HD);

    // Q fragments in registers (one-time global read, L2-resident)
    bf16x8 qf[2][2];
    for (int m = 0; m < 2; ++m)
        for (int dk = 0; dk < 2; ++dk)
            qf[m][dk] = *(const bf16x8*)(qg + hb +
                (size_t)(qt * 128 + w * 32 + m * 16 + q) * HD + dk * 32 + 8 * h);

    const int r0 = tid >> 3, r1 = (tid + 256) >> 3;
    const int cc0 = (tid & 7) * 8;
    // permuted V dest base: keys cc0..cc0+3 -> cA..cA+3, cc0+4..+7 -> cA+8..+11
    const int ntc = cc0 >> 4;
    const int cA = (ntc & 1) * 32 + ((cc0 >> 2) & 3) * 8 + (ntc >> 1) * 4;

    const __bf16 kOne = (__bf16)1.0f;
    const bf16x8 ones = {kOne, kOne, kOne, kOne, kOne, kOne, kOne, kOne};

    f32x4 acc[2][4] = {};
    f32x4 lsum[2] = {};

    // ---- prologue: tile 0 into buf 0; tile 1 into regs ----
    uint4 kp0 = *(const uint4*)(kg + hb + (size_t)r0 * HD + cc0);
    uint4 kp1 = *(const uint4*)(kg + hb + (size_t)r1 * HD + cc0);
    uint4 vp0 = *(const uint4*)(vT + hb + (size_t)r0 * SEQ + cc0);
    uint4 vp1 = *(const uint4*)(vT + hb + (size_t)r1 * SEQ + cc0);
    int mpre = (tid < 64) ? mask[tid] : 0;

    *(uint4*)&Ks[0][r0][cc0] = kp0;
    *(uint4*)&Ks[0][r1][cc0] = kp1;
    *(uint2*)&VTs[0][r0][cA]     = make_uint2(vp0.x, vp0.y);
    *(uint2*)&VTs[0][r0][cA + 8] = make_uint2(vp0.z, vp0.w);
    *(uint2*)&VTs[0][r1][cA]     = make_uint2(vp1.x, vp1.y);
    *(uint2*)&VTs[0][r1][cA + 8] = make_uint2(vp1.z, vp1.w);
    if (tid < 64) sb[0][tid] = mpre ? 0.f : -1e38f;

    kp0 = *(const uint4*)(kg + hb + (size_t)(64 * HD) + (size_t)r0 * HD + cc0);
    kp1 = *(const uint4*)(kg + hb + (size_t)(64 * HD) + (size_t)r1 * HD + cc0);
    vp0 = *(const uint4*)(vT + hb + (size_t)r0 * SEQ + 64 + cc0);
    vp1 = *(const uint4*)(vT + hb + (size_t)r1 * SEQ + 64 + cc0);
    if (tid < 64) mpre = mask[64 + tid];
    __syncthreads();

    for (int kt = 0; kt < 32; ++kt) {
        const int cur = kt & 1;
        if (kt < 31) {
            *(uint4*)&Ks[cur ^ 1][r0][cc0] = kp0;
            *(uint4*)&Ks[cur ^ 1][r1][cc0] = kp1;
            *(uint2*)&VTs[cur ^ 1][r0][cA]     = make_uint2(vp0.x, vp0.y);
            *(uint2*)&VTs[cur ^ 1][r0][cA + 8] = make_uint2(vp0.z, vp0.w);
            *(uint2*)&VTs[cur ^ 1][r1][cA]     = make_uint2(vp1.x, vp1.y);
            *(uint2*)&VTs[cur ^ 1][r1][cA + 8] = make_uint2(vp1.z, vp1.w);
            if (tid < 64) sb[cur ^ 1][tid] = mpre ? 0.f : -1e38f;
        }
        if (kt < 30) {
            const size_t ko = hb + (size_t)(kt + 2) * 64 * HD;
            kp0 = *(const uint4*)(kg + ko + (size_t)r0 * HD + cc0);
            kp1 = *(const uint4*)(kg + ko + (size_t)r1 * HD + cc0);
            vp0 = *(const uint4*)(vT + hb + (size_t)r0 * SEQ + (kt + 2) * 64 + cc0);
            vp1 = *(const uint4*)(vT + hb + (size_t)r1 * SEQ + (kt + 2) * 64 + cc0);
            if (tid < 64) mpre = mask[(kt + 2) * 64 + tid];
        }

        // S^T = K Q^T, accumulator init = per-key mask bias (vector read)
        f32x4 sacc[2][4];
        for (int nt = 0; nt < 4; ++nt) {
            f32x4 binit = *(const f32x4*)&sb[cur][nt * 16 + 4 * h];
            sacc[0][nt] = binit;
            sacc[1][nt] = binit;
        }
        for (int dk = 0; dk < 2; ++dk) {
            for (int nt = 0; nt < 4; ++nt) {
                bf16x8 kf = *(const bf16x8*)&Ks[cur][nt * 16 + q][dk * 32 + 8 * h];
                sacc[0][nt] = MFMA(kf, qf[0][dk], sacc[0][nt]);
                sacc[1][nt] = MFMA(kf, qf[1][dk], sacc[1][nt]);
            }
        }
        // p = exp2(s^T) packed straight into PV A-fragments (in registers)
        union pk_t { bf16x8 v; __hip_bfloat16 hh[8]; } pa[2][2];
        for (int m = 0; m < 2; ++m)
            for (int kk = 0; kk < 2; ++kk)
                for (int j = 0; j < 4; ++j) {
                    pa[m][kk].hh[j]     = __float2bfloat16(exp2f(sacc[m][kk][j]));
                    pa[m][kk].hh[j + 4] = __float2bfloat16(exp2f(sacc[m][kk + 2][j]));
                }
        // acc += P @ V ; lsum += P @ ones  (V columns permuted to match)
        for (int kk = 0; kk < 2; ++kk) {
            lsum[0] = MFMA(pa[0][kk].v, ones, lsum[0]);
            lsum[1] = MFMA(pa[1][kk].v, ones, lsum[1]);
            for (int dt = 0; dt < 4; ++dt) {
                bf16x8 bv = *(const bf16x8*)&VTs[cur][dt * 16 + q][kk * 32 + 8 * h];
                acc[0][dt] = MFMA(pa[0][kk].v, bv, acc[0][dt]);
                acc[1][dt] = MFMA(pa[1][kk].v, bv, acc[1][dt]);
            }
        }
        __syncthreads();   // writes to buf[cur^1] done; reads of buf[cur] done
    }

    // lane's lsum[m][jj] IS the row-sum for acc row jj of subtile m
    for (int m = 0; m < 2; ++m) {
        float rinv[4];
        for (int jj = 0; jj < 4; ++jj) rinv[jj] = 1.f / lsum[m][jj];
        const int ibase = qt * 128 + w * 32 + m * 16 + 4 * h;
        for (int dt = 0; dt < 4; ++dt) {
            int d = dt * 16 + q;
            union { __hip_bfloat16 hh[4]; uint2 u; } o;
            for (int jj = 0; jj < 4; ++jj)
                o.hh[jj] = __float2bfloat16(acc[m][dt][jj] * rinv[jj]);
            *(uint2*)(wvt + (size_t)g * (HD * SEQ) + (size_t)d * SEQ + ibase) = o.u;
        }
    }
}

// ---------------------------------------------------------------------------
// ws layout (26 MB peak): Xb [0,8MB) -> aliased by wvt after QKV GEMM;
// W bf16 [8,10MB); qb [10,18MB); kb [18,26MB).
// vT lives in d_out's first 8 MB (dead before gemm_out overwrites d_out).
// ---------------------------------------------------------------------------
extern "C" void kernel_launch(void* const* d_in, const int* in_sizes, int n_in,
                              void* d_out, int out_size, void* d_ws, size_t ws_size,
                              hipStream_t stream) {
    const float* lstm = (const float*)d_in[0];
    const int* mask = (const int*)d_in[1];
    const float* Wq = (const float*)d_in[2]; const float* bq = (const float*)d_in[3];
    const float* Wk = (const float*)d_in[4]; const float* bk = (const float*)d_in[5];
    const float* Wv = (const float*)d_in[6]; const float* bv = (const float*)d_in[7];
    const float* Wo = (const float*)d_in[8]; const float* bo = (const float*)d_in[9];
    float* out = (float*)d_out;

    const size_t NX = (size_t)MROWS * HID;    // 4M elems
    const size_t NW = (size_t)HID * HID;      // 256K elems
    __hip_bfloat16* Xb  = (__hip_bfloat16*)d_ws;            // 4M elems (8MB)
    __hip_bfloat16* Wqb = Xb + NX;                          // 256K
    __hip_bfloat16* Wkb = Wqb + NW;
    __hip_bfloat16* Wvb = Wkb + NW;
    __hip_bfloat16* Wob = Wvb + NW;
    __hip_bfloat16* qb  = Wob + NW;                         // 4M
    __hip_bfloat16* kb  = qb + NX;                          // 4M
    __hip_bfloat16* vT  = (__hip_bfloat16*)d_out;           // scratch in d_out[0,8MB)
    __hip_bfloat16* wvt = Xb;                               // alias: Xb dead after QKV GEMM

    conv_x<<<2048, 256, 0, stream>>>(lstm, Xb, (int)(NX / 4));
    conv_w<<<dim3(256, 4), 256, 0, stream>>>(Wq, Wk, Wv, Wo, Wqb);

    dim3 gg(MROWS / 64, HID / 64), bb(256);
    gemm_qkv_fused<<<gg, bb, 0, stream>>>(Xb, Wqb, Wkb, Wvb, bq, bk, bv, qb, kb, vT);
    attn<<<dim3(NG * (SEQ / 128)), bb, 0, stream>>>(qb, kb, vT, mask, wvt);
    gemm_out<<<gg, bb, 0, stream>>>(wvt, Wob, bo, out);
}

// Round 18
// 98.481 us; speedup vs baseline: 1.8421x; 1.1856x over previous
//
#include <hip/hip_runtime.h>
#include <hip/hip_bf16.h>

// Problem constants
#define HID 512
#define SEQ 2048
#define NG 32            // (B*NUM_HEADS) after the faithful-to-source flat reshape
#define HD 64
#define MROWS 8192       // B*SEQ
#define LDP 72           // padded LDS row stride (elems) = 144B
// 1/sqrt(512) * log2(e): folded into Q so softmax is exp2(s)
#define QSC 0.0637587178f
#define IDXN 2304        // padded idx length (2048 + slack)

typedef __bf16 bf16x8 __attribute__((ext_vector_type(8)));
typedef float f32x4 __attribute__((ext_vector_type(4)));

#define MFMA(a, b, c) __builtin_amdgcn_mfma_f32_16x16x32_bf16((a), (b), (c), 0, 0, 0)

// ---------------------------------------------------------------------------
// mask_scan: one block. hdr[0]=nvalid; idx=hdr+1 (gather list, 0-padded to
// IDXN); cidx=hdr+1+IDXN (scatter map: key i -> compact pos, -1 if masked).
// ---------------------------------------------------------------------------
__global__ __launch_bounds__(256) void mask_scan(const int* __restrict__ mask,
                                                 int* __restrict__ hdr) {
    __shared__ int s[256];
    const int tid = threadIdx.x;
    const int base = tid * 8;
    int loc[8], cnt = 0;
    for (int j = 0; j < 8; ++j) { loc[j] = cnt; cnt += (mask[base + j] != 0); }
    s[tid] = cnt;
    __syncthreads();
    for (int off = 1; off < 256; off <<= 1) {
        int v = (tid >= off) ? s[tid - off] : 0;
        __syncthreads();
        s[tid] += v;
        __syncthreads();
    }
    const int excl = s[tid] - cnt;
    const int nvalid = s[255];
    int* idx = hdr + 1;
    int* cidx = hdr + 1 + IDXN;
    for (int j = 0; j < 8; ++j) {
        int i = base + j;
        bool v = (mask[i] != 0);
        cidx[i] = v ? (excl + loc[j]) : -1;
        if (v) idx[excl + loc[j]] = i;
    }
    if (tid == 0) hdr[0] = nvalid;
    __syncthreads();
    for (int p = nvalid + tid; p < IDXN; p += 256) idx[p] = 0;
}

// ---------------------------------------------------------------------------
// vt_pad: zero vT's pad columns [nvalid, ceil64(nvalid)) for every head/dim.
// vT lives in d_out, which holds STALE fp32 output between timed replays;
// stale bytes reinterpreted as bf16 can be NaN, and 0*NaN = NaN would poison
// the PV accumulator (round-17 failure). Every byte attn reads must be
// written by the same call.
// ---------------------------------------------------------------------------
__global__ __launch_bounds__(256) void vt_pad(__hip_bfloat16* __restrict__ vT,
                                              const int* __restrict__ hdr) {
    const int nvalid = hdr[0];
    const int cend = (nvalid + 63) & ~63;
    if (cend == nvalid) return;
    const int g = blockIdx.x;
    const __hip_bfloat16 z = (__hip_bfloat16)0.0f;
    for (int d = 0; d < HD; ++d)
        for (int c = nvalid + threadIdx.x; c < cend; c += 256)
            vT[(size_t)g * (HD * SEQ) + (size_t)d * SEQ + c] = z;
}

// ---------------------------------------------------------------------------
// prep: f32 -> bf16 vectorized converts
// ---------------------------------------------------------------------------
__global__ __launch_bounds__(256) void conv_x(const float* __restrict__ src,
                                              __hip_bfloat16* __restrict__ dst, int n4) {
    int stride = gridDim.x * 256;
    for (int i = blockIdx.x * 256 + threadIdx.x; i < n4; i += stride) {
        float4 v = *(const float4*)(src + (size_t)i * 4);
        union { __hip_bfloat16 h[4]; uint2 u; } p;
        p.h[0] = __float2bfloat16(v.x); p.h[1] = __float2bfloat16(v.y);
        p.h[2] = __float2bfloat16(v.z); p.h[3] = __float2bfloat16(v.w);
        *(uint2*)(dst + (size_t)i * 4) = p.u;
    }
}

__global__ __launch_bounds__(256) void conv_w(const float* __restrict__ a,
                                              const float* __restrict__ b,
                                              const float* __restrict__ c,
                                              const float* __restrict__ d,
                                              __hip_bfloat16* __restrict__ out) {
    int which = blockIdx.y;
    const float* s = which == 0 ? a : (which == 1 ? b : (which == 2 ? c : d));
    __hip_bfloat16* o = out + (size_t)which * (HID * HID);
    int i = blockIdx.x * 256 + threadIdx.x;   // 65536 float4 per W
    float4 v = *(const float4*)(s + (size_t)i * 4);
    union { __hip_bfloat16 h[4]; uint2 u; } p;
    p.h[0] = __float2bfloat16(v.x); p.h[1] = __float2bfloat16(v.y);
    p.h[2] = __float2bfloat16(v.z); p.h[3] = __float2bfloat16(v.w);
    *(uint2*)(o + (size_t)i * 4) = p.u;
}

// ---------------------------------------------------------------------------
// Fused QKV GEMM, swapped MFMA operands (vector q/k stores). v written
// transposed AND column-compacted: only valid keys (cidx >= 0) are stored,
// at their compacted column. attn's V staging then reads contiguously.
// ---------------------------------------------------------------------------
__global__ __launch_bounds__(256) void gemm_qkv_fused(
        const __hip_bfloat16* __restrict__ Xb,
        const __hip_bfloat16* __restrict__ Wqb, const __hip_bfloat16* __restrict__ Wkb,
        const __hip_bfloat16* __restrict__ Wvb,
        const float* __restrict__ bq, const float* __restrict__ bk, const float* __restrict__ bv,
        const int* __restrict__ hdr,
        __hip_bfloat16* __restrict__ qout, __hip_bfloat16* __restrict__ kout,
        __hip_bfloat16* __restrict__ vT) {
    __shared__ __hip_bfloat16 Xs[64][LDP];
    __shared__ __hip_bfloat16 Wqs[64][LDP];
    __shared__ __hip_bfloat16 Wks[64][LDP];
    __shared__ __hip_bfloat16 Wvs[64][LDP];
    const int tid = threadIdx.x;
    const int w = tid >> 6, l = tid & 63;
    const int h = l >> 4, q = l & 15;
    const int row0 = blockIdx.x * 64, col0 = blockIdx.y * 64;

    const int r0 = tid >> 3, r1 = (tid + 256) >> 3;
    const int cc0 = (tid & 7) * 8;
    uint4 px0, px1, pq0, pq1, pk0, pk1, pv0, pv1;
    {
        px0 = *(const uint4*)(Xb  + (size_t)(row0 + r0) * HID + cc0);
        px1 = *(const uint4*)(Xb  + (size_t)(row0 + r1) * HID + cc0);
        pq0 = *(const uint4*)(Wqb + (size_t)(col0 + r0) * HID + cc0);
        pq1 = *(const uint4*)(Wqb + (size_t)(col0 + r1) * HID + cc0);
        pk0 = *(const uint4*)(Wkb + (size_t)(col0 + r0) * HID + cc0);
        pk1 = *(const uint4*)(Wkb + (size_t)(col0 + r1) * HID + cc0);
        pv0 = *(const uint4*)(Wvb + (size_t)(col0 + r0) * HID + cc0);
        pv1 = *(const uint4*)(Wvb + (size_t)(col0 + r1) * HID + cc0);
    }

    f32x4 aq[4] = {}, ak[4] = {}, av[4] = {};
    for (int kt = 0; kt < 8; ++kt) {
        __syncthreads();
        *(uint4*)&Xs[r0][cc0]  = px0;  *(uint4*)&Xs[r1][cc0]  = px1;
        *(uint4*)&Wqs[r0][cc0] = pq0;  *(uint4*)&Wqs[r1][cc0] = pq1;
        *(uint4*)&Wks[r0][cc0] = pk0;  *(uint4*)&Wks[r1][cc0] = pk1;
        *(uint4*)&Wvs[r0][cc0] = pv0;  *(uint4*)&Wvs[r1][cc0] = pv1;
        __syncthreads();
        if (kt < 7) {
            size_t go = (size_t)(kt + 1) * 64 + cc0;
            px0 = *(const uint4*)(Xb  + (size_t)(row0 + r0) * HID + go);
            px1 = *(const uint4*)(Xb  + (size_t)(row0 + r1) * HID + go);
            pq0 = *(const uint4*)(Wqb + (size_t)(col0 + r0) * HID + go);
            pq1 = *(const uint4*)(Wqb + (size_t)(col0 + r1) * HID + go);
            pk0 = *(const uint4*)(Wkb + (size_t)(col0 + r0) * HID + go);
            pk1 = *(const uint4*)(Wkb + (size_t)(col0 + r1) * HID + go);
            pv0 = *(const uint4*)(Wvb + (size_t)(col0 + r0) * HID + go);
            pv1 = *(const uint4*)(Wvb + (size_t)(col0 + r1) * HID + go);
        }
        for (int dk = 0; dk < 2; ++dk) {
            bf16x8 x = *(const bf16x8*)&Xs[w * 16 + q][dk * 32 + 8 * h];
            for (int nt = 0; nt < 4; ++nt) {
                int rr = nt * 16 + q, cc = dk * 32 + 8 * h;
                aq[nt] = MFMA(*(const bf16x8*)&Wqs[rr][cc], x, aq[nt]);
                ak[nt] = MFMA(*(const bf16x8*)&Wks[rr][cc], x, ak[nt]);
                av[nt] = MFMA(*(const bf16x8*)&Wvs[rr][cc], x, av[nt]);
            }
        }
    }
    // epilogue: lane row m = row0 + w*16 + q; cols n = col0 + nt*16 + 4h + jj
    const int m = row0 + w * 16 + q;
    const int g = row0 >> 8;
    const int irow = ((m & 255) << 3) + (int)blockIdx.y;   // key index i
    const int ci = hdr[1 + IDXN + irow];                   // compact column (-1 = masked)
    for (int nt = 0; nt < 4; ++nt) {
        int nb = col0 + nt * 16 + 4 * h;
        float4 b4q = *(const float4*)(bq + nb);
        float4 b4k = *(const float4*)(bk + nb);
        float4 b4v = *(const float4*)(bv + nb);
        const float* bqf = (const float*)&b4q;
        const float* bkf = (const float*)&b4k;
        const float* bvf = (const float*)&b4v;
        union { __hip_bfloat16 hh[4]; uint2 u; } oq, ok;
        for (int jj = 0; jj < 4; ++jj) {
            oq.hh[jj] = __float2bfloat16((aq[nt][jj] + bqf[jj]) * QSC);
            ok.hh[jj] = __float2bfloat16(ak[nt][jj] + bkf[jj]);
        }
        *(uint2*)(qout + (size_t)m * HID + nb) = oq.u;
        *(uint2*)(kout + (size_t)m * HID + nb) = ok.u;
        if (ci >= 0) {
            int db = nb & 63;
            for (int jj = 0; jj < 4; ++jj)
                vT[(size_t)g * (HD * SEQ) + (size_t)(db + jj) * SEQ + ci] =
                    __float2bfloat16(av[nt][jj] + bvf[jj]);
        }
    }
}

// ---------------------------------------------------------------------------
// GEMM: out_f32[M x 512] = X_bf16 @ Wo_bf16^T + bo. Swapped operands ->
// float4 (16B) contiguous output stores.
// ---------------------------------------------------------------------------
__global__ __launch_bounds__(256) void gemm_out(const __hip_bfloat16* __restrict__ X,
                                                const __hip_bfloat16* __restrict__ W,
                                                const float* __restrict__ bias,
                                                float* __restrict__ out) {
    __shared__ __hip_bfloat16 Xs[64][LDP];
    __shared__ __hip_bfloat16 Ws[64][LDP];
    const int tid = threadIdx.x;
    const int w = tid >> 6, l = tid & 63;
    const int h = l >> 4, q = l & 15;
    const int row0 = blockIdx.x * 64, col0 = blockIdx.y * 64;

    const int r0 = tid >> 3, r1 = (tid + 256) >> 3;
    const int cc0 = (tid & 7) * 8;
    uint4 px0 = *(const uint4*)(X + (size_t)(row0 + r0) * HID + cc0);
    uint4 px1 = *(const uint4*)(X + (size_t)(row0 + r1) * HID + cc0);
    uint4 pw0 = *(const uint4*)(W + (size_t)(col0 + r0) * HID + cc0);
    uint4 pw1 = *(const uint4*)(W + (size_t)(col0 + r1) * HID + cc0);

    f32x4 acc[4] = {};
    for (int kt = 0; kt < 8; ++kt) {
        __syncthreads();
        *(uint4*)&Xs[r0][cc0] = px0;  *(uint4*)&Xs[r1][cc0] = px1;
        *(uint4*)&Ws[r0][cc0] = pw0;  *(uint4*)&Ws[r1][cc0] = pw1;
        __syncthreads();
        if (kt < 7) {
            size_t go = (size_t)(kt + 1) * 64 + cc0;
            px0 = *(const uint4*)(X + (size_t)(row0 + r0) * HID + go);
            px1 = *(const uint4*)(X + (size_t)(row0 + r1) * HID + go);
            pw0 = *(const uint4*)(W + (size_t)(col0 + r0) * HID + go);
            pw1 = *(const uint4*)(W + (size_t)(col0 + r1) * HID + go);
        }
        for (int dk = 0; dk < 2; ++dk) {
            bf16x8 x = *(const bf16x8*)&Xs[w * 16 + q][dk * 32 + 8 * h];
            for (int nt = 0; nt < 4; ++nt) {
                bf16x8 b = *(const bf16x8*)&Ws[nt * 16 + q][dk * 32 + 8 * h];
                acc[nt] = MFMA(b, x, acc[nt]);
            }
        }
    }
    const int m = row0 + w * 16 + q;
    for (int nt = 0; nt < 4; ++nt) {
        int nb = col0 + nt * 16 + 4 * h;
        float4 b4 = *(const float4*)(bias + nb);
        float4 o = make_float4(acc[nt][0] + b4.x, acc[nt][1] + b4.y,
                               acc[nt][2] + b4.z, acc[nt][3] + b4.w);
        *(float4*)(out + (size_t)m * HID + nb) = o;
    }
}

// ---------------------------------------------------------------------------
// Attention over COMPACTED keys: ntiles = ceil(nvalid/64). K rows gathered
// via idx; V compacted at write (+ zeroed pads via vt_pad). Tail pad slots
// masked via sbias. Swapped-QK^T in-register softmax (round-12/16 structure).
// ---------------------------------------------------------------------------
__global__ __launch_bounds__(256) void attn(const __hip_bfloat16* __restrict__ qg,
                                            const __hip_bfloat16* __restrict__ kg,
                                            const __hip_bfloat16* __restrict__ vT,
                                            const int* __restrict__ hdr,
                                            __hip_bfloat16* __restrict__ wvt) {
    __shared__ __hip_bfloat16 Ks[2][64][LDP];
    __shared__ __hip_bfloat16 VTs[2][64][LDP];
    __shared__ float sb[2][64];

    const int tid = threadIdx.x;
    const int w = tid >> 6, l = tid & 63;
    const int h = l >> 4, q = l & 15;
    // XCD-chunked swizzle: 512 blocks % 8 == 0 -> bijective
    const int bid = (blockIdx.x & 7) * 64 + (blockIdx.x >> 3);
    const int g = bid >> 4, qt = bid & 15;
    const size_t hb = (size_t)g * (SEQ * HD);

    const int nvalid = hdr[0];
    const int ntiles = (nvalid + 63) >> 6;
    const int* idx = hdr + 1;

    // Q fragments in registers (one-time global read, L2-resident)
    bf16x8 qf[2][2];
    for (int m = 0; m < 2; ++m)
        for (int dk = 0; dk < 2; ++dk)
            qf[m][dk] = *(const bf16x8*)(qg + hb +
                (size_t)(qt * 128 + w * 32 + m * 16 + q) * HD + dk * 32 + 8 * h);

    const int r0 = tid >> 3, r1 = (tid + 256) >> 3;
    const int cc0 = (tid & 7) * 8;
    // permuted V dest base: keys cc0..cc0+3 -> cA..cA+3, cc0+4..+7 -> cA+8..+11
    const int ntc = cc0 >> 4;
    const int cA = (ntc & 1) * 32 + ((cc0 >> 2) & 3) * 8 + (ntc >> 1) * 4;

    const __bf16 kOne = (__bf16)1.0f;
    const bf16x8 ones = {kOne, kOne, kOne, kOne, kOne, kOne, kOne, kOne};

    f32x4 acc[2][4] = {};
    f32x4 lsum[2] = {};

    // ---- prologue: tile 0 into buf 0; tile 1 into regs ----
    uint4 kp0 = *(const uint4*)(kg + hb + (size_t)idx[r0] * HD + cc0);
    uint4 kp1 = *(const uint4*)(kg + hb + (size_t)idx[r1] * HD + cc0);
    uint4 vp0 = *(const uint4*)(vT + hb + (size_t)r0 * SEQ + cc0);
    uint4 vp1 = *(const uint4*)(vT + hb + (size_t)r1 * SEQ + cc0);

    *(uint4*)&Ks[0][r0][cc0] = kp0;
    *(uint4*)&Ks[0][r1][cc0] = kp1;
    *(uint2*)&VTs[0][r0][cA]     = make_uint2(vp0.x, vp0.y);
    *(uint2*)&VTs[0][r0][cA + 8] = make_uint2(vp0.z, vp0.w);
    *(uint2*)&VTs[0][r1][cA]     = make_uint2(vp1.x, vp1.y);
    *(uint2*)&VTs[0][r1][cA + 8] = make_uint2(vp1.z, vp1.w);
    if (tid < 64) sb[0][tid] = (tid < nvalid) ? 0.f : -1e38f;

    kp0 = *(const uint4*)(kg + hb + (size_t)idx[64 + r0] * HD + cc0);
    kp1 = *(const uint4*)(kg + hb + (size_t)idx[64 + r1] * HD + cc0);
    vp0 = *(const uint4*)(vT + hb + (size_t)r0 * SEQ + 64 + cc0);
    vp1 = *(const uint4*)(vT + hb + (size_t)r1 * SEQ + 64 + cc0);
    float sbpre = (64 + tid < nvalid) ? 0.f : -1e38f;
    __syncthreads();

    for (int kt = 0; kt < ntiles; ++kt) {
        const int cur = kt & 1;
        if (kt < ntiles - 1) {
            *(uint4*)&Ks[cur ^ 1][r0][cc0] = kp0;
            *(uint4*)&Ks[cur ^ 1][r1][cc0] = kp1;
            *(uint2*)&VTs[cur ^ 1][r0][cA]     = make_uint2(vp0.x, vp0.y);
            *(uint2*)&VTs[cur ^ 1][r0][cA + 8] = make_uint2(vp0.z, vp0.w);
            *(uint2*)&VTs[cur ^ 1][r1][cA]     = make_uint2(vp1.x, vp1.y);
            *(uint2*)&VTs[cur ^ 1][r1][cA + 8] = make_uint2(vp1.z, vp1.w);
            if (tid < 64) sb[cur ^ 1][tid] = sbpre;
        }
        if (kt < ntiles - 2) {
            const int tn = (kt + 2) * 64;
            kp0 = *(const uint4*)(kg + hb + (size_t)idx[tn + r0] * HD + cc0);
            kp1 = *(const uint4*)(kg + hb + (size_t)idx[tn + r1] * HD + cc0);
            vp0 = *(const uint4*)(vT + hb + (size_t)r0 * SEQ + tn + cc0);
            vp1 = *(const uint4*)(vT + hb + (size_t)r1 * SEQ + tn + cc0);
            sbpre = (tn + tid < nvalid) ? 0.f : -1e38f;
        }

        // S^T = K Q^T, accumulator init = per-key mask bias (vector read)
        f32x4 sacc[2][4];
        for (int nt = 0; nt < 4; ++nt) {
            f32x4 binit = *(const f32x4*)&sb[cur][nt * 16 + 4 * h];
            sacc[0][nt] = binit;
            sacc[1][nt] = binit;
        }
        for (int dk = 0; dk < 2; ++dk) {
            for (int nt = 0; nt < 4; ++nt) {
                bf16x8 kf = *(const bf16x8*)&Ks[cur][nt * 16 + q][dk * 32 + 8 * h];
                sacc[0][nt] = MFMA(kf, qf[0][dk], sacc[0][nt]);
                sacc[1][nt] = MFMA(kf, qf[1][dk], sacc[1][nt]);
            }
        }
        // p = exp2(s^T) packed straight into PV A-fragments (in registers)
        union pk_t { bf16x8 v; __hip_bfloat16 hh[8]; } pa[2][2];
        for (int m = 0; m < 2; ++m)
            for (int kk = 0; kk < 2; ++kk)
                for (int j = 0; j < 4; ++j) {
                    pa[m][kk].hh[j]     = __float2bfloat16(exp2f(sacc[m][kk][j]));
                    pa[m][kk].hh[j + 4] = __float2bfloat16(exp2f(sacc[m][kk + 2][j]));
                }
        // acc += P @ V ; lsum += P @ ones  (V columns permuted to match)
        for (int kk = 0; kk < 2; ++kk) {
            lsum[0] = MFMA(pa[0][kk].v, ones, lsum[0]);
            lsum[1] = MFMA(pa[1][kk].v, ones, lsum[1]);
            for (int dt = 0; dt < 4; ++dt) {
                bf16x8 bv = *(const bf16x8*)&VTs[cur][dt * 16 + q][kk * 32 + 8 * h];
                acc[0][dt] = MFMA(pa[0][kk].v, bv, acc[0][dt]);
                acc[1][dt] = MFMA(pa[1][kk].v, bv, acc[1][dt]);
            }
        }
        __syncthreads();   // writes to buf[cur^1] done; reads of buf[cur] done
    }

    // lane's lsum[m][jj] IS the row-sum for acc row jj of subtile m
    for (int m = 0; m < 2; ++m) {
        float rinv[4];
        for (int jj = 0; jj < 4; ++jj) rinv[jj] = 1.f / lsum[m][jj];
        const int ibase = qt * 128 + w * 32 + m * 16 + 4 * h;
        for (int dt = 0; dt < 4; ++dt) {
            int d = dt * 16 + q;
            union { __hip_bfloat16 hh[4]; uint2 u; } o;
            for (int jj = 0; jj < 4; ++jj)
                o.hh[jj] = __float2bfloat16(acc[m][dt][jj] * rinv[jj]);
            *(uint2*)(wvt + (size_t)g * (HD * SEQ) + (size_t)d * SEQ + ibase) = o.u;
        }
    }
}

// ---------------------------------------------------------------------------
// ws layout (26MB + 18KB): Xb [0,8MB) -> aliased by wvt after QKV GEMM;
// W bf16 [8,10MB); qb [10,18MB); kb [18,26MB); hdr [26MB, +18KB).
// vT lives in d_out's first 8 MB (dead before gemm_out overwrites d_out);
// vt_pad zeroes its pad columns every call (no stale-state reads).
// ---------------------------------------------------------------------------
extern "C" void kernel_launch(void* const* d_in, const int* in_sizes, int n_in,
                              void* d_out, int out_size, void* d_ws, size_t ws_size,
                              hipStream_t stream) {
    const float* lstm = (const float*)d_in[0];
    const int* mask = (const int*)d_in[1];
    const float* Wq = (const float*)d_in[2]; const float* bq = (const float*)d_in[3];
    const float* Wk = (const float*)d_in[4]; const float* bk = (const float*)d_in[5];
    const float* Wv = (const float*)d_in[6]; const float* bv = (const float*)d_in[7];
    const float* Wo = (const float*)d_in[8]; const float* bo = (const float*)d_in[9];
    float* out = (float*)d_out;

    const size_t NX = (size_t)MROWS * HID;    // 4M elems
    const size_t NW = (size_t)HID * HID;      // 256K elems
    __hip_bfloat16* Xb  = (__hip_bfloat16*)d_ws;            // 4M elems (8MB)
    __hip_bfloat16* Wqb = Xb + NX;                          // 256K
    __hip_bfloat16* Wkb = Wqb + NW;
    __hip_bfloat16* Wvb = Wkb + NW;
    __hip_bfloat16* Wob = Wvb + NW;
    __hip_bfloat16* qb  = Wob + NW;                         // 4M
    __hip_bfloat16* kb  = qb + NX;                          // 4M
    int*            hdr = (int*)(kb + NX);                  // 1 + IDXN + 2048 ints
    __hip_bfloat16* vT  = (__hip_bfloat16*)d_out;           // scratch in d_out[0,8MB)
    __hip_bfloat16* wvt = Xb;                               // alias: Xb dead after QKV GEMM

    mask_scan<<<1, 256, 0, stream>>>(mask, hdr);
    conv_x<<<2048, 256, 0, stream>>>(lstm, Xb, (int)(NX / 4));
    conv_w<<<dim3(256, 4), 256, 0, stream>>>(Wq, Wk, Wv, Wo, Wqb);

    dim3 gg(MROWS / 64, HID / 64), bb(256);
    gemm_qkv_fused<<<gg, bb, 0, stream>>>(Xb, Wqb, Wkb, Wvb, bq, bk, bv, hdr, qb, kb, vT);
    vt_pad<<<dim3(NG), bb, 0, stream>>>(vT, hdr);
    attn<<<dim3(NG * (SEQ / 128)), bb, 0, stream>>>(qb, kb, vT, hdr, wvt);
    gemm_out<<<gg, bb, 0, stream>>>(wvt, Wob, bo, out);
}